// Round 1
// baseline (120.500 us; speedup 1.0000x reference)
//
#include <hip/hip_runtime.h>
#include <hip/hip_bf16.h>
#include <stdint.h>

typedef __bf16 bf16_t;
typedef __bf16 bf16x8 __attribute__((ext_vector_type(8)));
typedef float f32x4 __attribute__((ext_vector_type(4)));

#define L2E 1.44269504088896340736f

static __device__ __forceinline__ f32x4 mfma16(bf16x8 a, bf16x8 b, f32x4 c) {
  return __builtin_amdgcn_mfma_f32_16x16x32_bf16(a, b, c, 0, 0, 0);
}

// ---------------- kernel 0: weights -> bf16, transposed to [proj][n=64][k=1024] ----
// proj 0 (Q) folded scale 1/sqrt(64) = 0.125
__global__ __launch_bounds__(256) void wt_kernel(const float* __restrict__ Wq,
                                                 const float* __restrict__ Wk,
                                                 const float* __restrict__ Wv,
                                                 bf16_t* __restrict__ Wt) {
  int gid = blockIdx.x * 256 + threadIdx.x;  // 0 .. 196607
  int proj = gid >> 16;
  int rem = gid & 65535;          // = k*64 + n (row-major read, coalesced)
  int k = rem >> 6, n = rem & 63;
  const float* W = (proj == 0) ? Wq : (proj == 1) ? Wk : Wv;
  float v = W[rem];
  if (proj == 0) v *= 0.125f;
  Wt[proj * 65536 + n * 1024 + k] = (bf16_t)v;
}

// ---------------- kernel 1: QKV projection, 1 wave/block, 16 rows x 64 cols -------
// A-frags straight from global f32 (converted in-reg), B-frags from L2-resident Wt.
__global__ __launch_bounds__(64) void proj_kernel(
    const float* __restrict__ Xq, const float* __restrict__ Xk, const float* __restrict__ Xv,
    const bf16_t* __restrict__ Wt,
    bf16_t* __restrict__ Qb, bf16_t* __restrict__ Kb, bf16_t* __restrict__ Vt) {
  int proj = blockIdx.y;
  const float* X = (proj == 0) ? Xq : (proj == 1) ? Xk : Xv;
  int lane = threadIdx.x;
  int l15 = lane & 15, g = lane >> 4;
  int m0 = blockIdx.x * 16;
  const float* xrow = X + (size_t)(m0 + l15) * 1024 + g * 8;
  const bf16_t* wt = Wt + proj * 65536;

  f32x4 acc[4] = {};
#pragma unroll 4
  for (int k = 0; k < 1024; k += 32) {
    float4 a0 = *(const float4*)(xrow + k);
    float4 a1 = *(const float4*)(xrow + k + 4);
    bf16x8 af;
    af[0] = (bf16_t)a0.x; af[1] = (bf16_t)a0.y; af[2] = (bf16_t)a0.z; af[3] = (bf16_t)a0.w;
    af[4] = (bf16_t)a1.x; af[5] = (bf16_t)a1.y; af[6] = (bf16_t)a1.z; af[7] = (bf16_t)a1.w;
#pragma unroll
    for (int ct = 0; ct < 4; ++ct) {
      bf16x8 bfr = *(const bf16x8*)(wt + (ct * 16 + l15) * 1024 + k + g * 8);
      acc[ct] = mfma16(af, bfr, acc[ct]);
    }
  }
  // D layout: row = g*4 + r, col = ct*16 + l15
#pragma unroll
  for (int ct = 0; ct < 4; ++ct) {
#pragma unroll
    for (int r = 0; r < 4; ++r) {
      int row = m0 + g * 4 + r;
      int col = ct * 16 + l15;
      bf16_t v = (bf16_t)acc[ct][r];
      if (proj == 0) {
        Qb[(size_t)row * 64 + col] = v;          // pre-scaled via Wt
      } else if (proj == 1) {
        Kb[(size_t)row * 64 + col] = v;
      } else {
        int b = row >> 11, s = row & 2047;
        Vt[((size_t)(b * 64 + col)) * 2048 + s] = v;   // V stored transposed [b][d][s]
      }
    }
  }
}

// ---------------- kernel 2: causal flash attention ---------------------------------
// block = 256 thr (4 waves), QBLK=64 (wave w owns rows w*16..w*16+15), KVBLK=64.
__global__ __launch_bounds__(256) void attn_kernel(
    const bf16_t* __restrict__ Qb, const bf16_t* __restrict__ Kb,
    const bf16_t* __restrict__ Vt, float* __restrict__ Out) {
  __shared__ alignas(16) char Ksm[8192];   // [64 k][64 d] bf16, XOR-swizzled
  __shared__ alignas(16) char Vsm[8192];   // [64 d][64 k] bf16, XOR-swizzled
  __shared__ alignas(16) char Psm[8192];   // 4 waves x [16 q][64 k] bf16, swizzled

  int b = blockIdx.y;
  int qt = blockIdx.x;
  int q0 = qt * 64;
  int tid = threadIdx.x;
  int w = tid >> 6, lane = tid & 63;
  int l15 = lane & 15, g = lane >> 4;
  char* Pw = Psm + w * 2048;

  // Q fragments in registers (A-operand; rows w*16 + l15)
  size_t qrow = (size_t)(b * 2048 + q0 + w * 16 + l15) * 64;
  bf16x8 qf0 = *(const bf16x8*)(Qb + qrow + g * 8);
  bf16x8 qf1 = *(const bf16x8*)(Qb + qrow + 32 + g * 8);

  float m_run[4] = {-1e30f, -1e30f, -1e30f, -1e30f};
  float l_run[4] = {0.f, 0.f, 0.f, 0.f};
  f32x4 acc_o[4] = {};

  int sr = tid >> 2;                // stage row (k for K, d for V)
  int sc = (tid & 3) * 16;          // stage col start
  int ssw = (sr & 7) << 4;
  const bf16_t* kbase = Kb + (size_t)(b * 2048) * 64;
  const bf16_t* vbase = Vt + (size_t)(b * 64) * 2048;

  for (int kv = 0; kv <= qt; ++kv) {
    __syncthreads();
    {
      const uint4* ks = (const uint4*)(kbase + (size_t)(kv * 64 + sr) * 64 + sc);
      uint4 k0v = ks[0], k1v = ks[1];
      const uint4* vs = (const uint4*)(vbase + (size_t)sr * 2048 + kv * 64 + sc);
      uint4 v0v = vs[0], v1v = vs[1];
      *(uint4*)(Ksm + sr * 128 + ((sc * 2) ^ ssw)) = k0v;
      *(uint4*)(Ksm + sr * 128 + ((sc * 2 + 16) ^ ssw)) = k1v;
      *(uint4*)(Vsm + sr * 128 + ((sc * 2) ^ ssw)) = v0v;
      *(uint4*)(Vsm + sr * 128 + ((sc * 2 + 16) ^ ssw)) = v1v;
    }
    __syncthreads();

    // S = Q K^T (already includes 1/sqrt(64) via Q)
    f32x4 s[4] = {};
#pragma unroll
    for (int ct = 0; ct < 4; ++ct) {
      int kr = ct * 16 + l15;
      int swk = (kr & 7) << 4;
      bf16x8 kf0 = *(const bf16x8*)(Ksm + kr * 128 + ((g * 16) ^ swk));
      bf16x8 kf1 = *(const bf16x8*)(Ksm + kr * 128 + ((64 + g * 16) ^ swk));
      s[ct] = mfma16(qf0, kf0, s[ct]);
      s[ct] = mfma16(qf1, kf1, s[ct]);
    }

    if (kv == qt) {  // causal mask only ever intersects the diagonal tile
#pragma unroll
      for (int ct = 0; ct < 4; ++ct) {
#pragma unroll
        for (int r = 0; r < 4; ++r) {
          int kg_ = kv * 64 + ct * 16 + l15;
          int qg_ = q0 + w * 16 + g * 4 + r;
          if (kg_ > qg_) s[ct][r] = -1e30f;
        }
      }
    }

    // online softmax (row r lives in the 16-lane group, reg r)
#pragma unroll
    for (int r = 0; r < 4; ++r) {
      float mx = fmaxf(fmaxf(s[0][r], s[1][r]), fmaxf(s[2][r], s[3][r]));
      mx = fmaxf(mx, __shfl_xor(mx, 1, 64));
      mx = fmaxf(mx, __shfl_xor(mx, 2, 64));
      mx = fmaxf(mx, __shfl_xor(mx, 4, 64));
      mx = fmaxf(mx, __shfl_xor(mx, 8, 64));
      float mnew = fmaxf(m_run[r], mx);
      float scale = exp2f((m_run[r] - mnew) * L2E);
      m_run[r] = mnew;
      float ps = 0.f;
      int qrl = g * 4 + r;
      char* pb = Pw + qrl * 128;
      int swp = (qrl & 7) << 4;
#pragma unroll
      for (int ct = 0; ct < 4; ++ct) {
        float p = exp2f((s[ct][r] - mnew) * L2E);
        ps += p;
        *(bf16_t*)(pb + ((ct * 32 + l15 * 2) ^ swp)) = (bf16_t)p;
      }
      ps += __shfl_xor(ps, 1, 64);
      ps += __shfl_xor(ps, 2, 64);
      ps += __shfl_xor(ps, 4, 64);
      ps += __shfl_xor(ps, 8, 64);
      l_run[r] = l_run[r] * scale + ps;
#pragma unroll
      for (int dt = 0; dt < 4; ++dt) acc_o[dt][r] *= scale;
    }

    // O += P V  (A = P from per-wave LDS, B = V^T tile)
    int swpr = (l15 & 7) << 4;
#pragma unroll
    for (int ks = 0; ks < 2; ++ks) {
      bf16x8 pf = *(const bf16x8*)(Pw + l15 * 128 + ((ks * 64 + g * 16) ^ swpr));
#pragma unroll
      for (int dt = 0; dt < 4; ++dt) {
        int vr = dt * 16 + l15;
        int swv = (vr & 7) << 4;
        bf16x8 vf = *(const bf16x8*)(Vsm + vr * 128 + ((ks * 64 + g * 16) ^ swv));
        acc_o[dt] = mfma16(pf, vf, acc_o[dt]);
      }
    }
  }

  // epilogue: divide by l, write f32
#pragma unroll
  for (int r = 0; r < 4; ++r) {
    float inv = 1.0f / l_run[r];
    size_t orow = (size_t)(b * 2048 + q0 + w * 16 + g * 4 + r) * 64;
#pragma unroll
    for (int dt = 0; dt < 4; ++dt)
      Out[orow + dt * 16 + l15] = acc_o[dt][r] * inv;
  }
}

extern "C" void kernel_launch(void* const* d_in, const int* in_sizes, int n_in,
                              void* d_out, int out_size, void* d_ws, size_t ws_size,
                              hipStream_t stream) {
  const float* Xk = (const float*)d_in[0];
  const float* Xv = (const float*)d_in[1];
  const float* Xq = (const float*)d_in[2];
  const float* Wq = (const float*)d_in[3];
  const float* Wk = (const float*)d_in[4];
  const float* Wv = (const float*)d_in[5];
  float* Out = (float*)d_out;

  bf16_t* ws = (bf16_t*)d_ws;
  bf16_t* Qb = ws;                 // [8192][64]   bf16, pre-scaled by 0.125
  bf16_t* Kb = ws + 524288;        // [8192][64]   bf16
  bf16_t* Vt = ws + 1048576;       // [4][64][2048] bf16 (V transposed)
  bf16_t* Wt = ws + 1572864;       // [3][64][1024] bf16 (weights transposed)

  wt_kernel<<<dim3(768), dim3(256), 0, stream>>>(Wq, Wk, Wv, Wt);
  proj_kernel<<<dim3(512, 3), dim3(64), 0, stream>>>(Xq, Xk, Xv, Wt, Qb, Kb, Vt);
  attn_kernel<<<dim3(32, 4), dim3(256), 0, stream>>>(Qb, Kb, Vt, Out);
}

// Round 2
// 78.796 us; speedup vs baseline: 1.5293x; 1.5293x over previous
//
#include <hip/hip_runtime.h>
#include <hip/hip_bf16.h>
#include <stdint.h>

typedef __bf16 bf16_t;
typedef __bf16 bf16x8 __attribute__((ext_vector_type(8)));
typedef float f32x4 __attribute__((ext_vector_type(4)));

#define L2E 1.44269504088896340736f

static __device__ __forceinline__ f32x4 mfma16(bf16x8 a, bf16x8 b, f32x4 c) {
  return __builtin_amdgcn_mfma_f32_16x16x32_bf16(a, b, c, 0, 0, 0);
}

// ---------------- kernel 0: weights -> bf16, transposed to [proj][n=64][k=1024] ----
// proj 0 (Q) folds the 1/sqrt(64) scale.
__global__ __launch_bounds__(256) void wt_kernel(const float* __restrict__ Wq,
                                                 const float* __restrict__ Wk,
                                                 const float* __restrict__ Wv,
                                                 bf16_t* __restrict__ Wt) {
  int gid = blockIdx.x * 256 + threadIdx.x;  // 0 .. 196607
  int proj = gid >> 16;
  int rem = gid & 65535;          // = k*64 + n (row-major read, coalesced)
  int k = rem >> 6, n = rem & 63;
  const float* W = (proj == 0) ? Wq : (proj == 1) ? Wk : Wv;
  float v = W[rem];
  if (proj == 0) v *= 0.125f;
  Wt[proj * 65536 + n * 1024 + k] = (bf16_t)v;
}

// ---------------- kernel 1: QKV projection -----------------------------------------
// grid (128, 3), block 256 (4 waves); wave w computes rows m0+w*16 .. +15, 64 cols.
// Outputs staged through LDS so all global stores are coalesced 32B chunks.
__global__ __launch_bounds__(256) void proj_kernel(
    const float* __restrict__ Xq, const float* __restrict__ Xk, const float* __restrict__ Xv,
    const bf16_t* __restrict__ Wt,
    bf16_t* __restrict__ Qb, bf16_t* __restrict__ Kb, bf16_t* __restrict__ Vt) {
  __shared__ bf16_t Sm[64 * 72];   // 64 rows, stride 72 (pad kills read conflicts)
  int proj = blockIdx.y;
  const float* X = (proj == 0) ? Xq : (proj == 1) ? Xk : Xv;
  int tid = threadIdx.x;
  int w = tid >> 6, lane = tid & 63;
  int l15 = lane & 15, g = lane >> 4;
  int m0 = blockIdx.x * 64;
  const float* xrow = X + (size_t)(m0 + w * 16 + l15) * 1024 + g * 8;
  const bf16_t* wt = Wt + proj * 65536;

  f32x4 acc[4] = {};
#pragma unroll 4
  for (int k = 0; k < 1024; k += 32) {
    float4 a0 = *(const float4*)(xrow + k);
    float4 a1 = *(const float4*)(xrow + k + 4);
    bf16x8 af;
    af[0] = (bf16_t)a0.x; af[1] = (bf16_t)a0.y; af[2] = (bf16_t)a0.z; af[3] = (bf16_t)a0.w;
    af[4] = (bf16_t)a1.x; af[5] = (bf16_t)a1.y; af[6] = (bf16_t)a1.z; af[7] = (bf16_t)a1.w;
#pragma unroll
    for (int ct = 0; ct < 4; ++ct) {
      bf16x8 bfr = *(const bf16x8*)(wt + (ct * 16 + l15) * 1024 + k + g * 8);
      acc[ct] = mfma16(af, bfr, acc[ct]);
    }
  }
  // C layout: row = g*4+r, col = ct*16+l15  -> stage in LDS
#pragma unroll
  for (int ct = 0; ct < 4; ++ct)
#pragma unroll
    for (int r = 0; r < 4; ++r)
      Sm[(w * 16 + g * 4 + r) * 72 + ct * 16 + l15] = (bf16_t)acc[ct][r];
  __syncthreads();

  if (proj < 2) {
    bf16_t* Ob = (proj == 0) ? Qb : Kb;
    int row = tid >> 2, c0 = (tid & 3) * 16;
    uint4 v0 = *(const uint4*)&Sm[row * 72 + c0];
    uint4 v1 = *(const uint4*)&Sm[row * 72 + c0 + 8];
    *(uint4*)&Ob[(size_t)(m0 + row) * 64 + c0] = v0;
    *(uint4*)&Ob[(size_t)(m0 + row) * 64 + c0 + 8] = v1;
  } else {
    int d = tid >> 2, s0 = (tid & 3) * 16;
    int b = m0 >> 11;
    int sbase = (m0 & 2047) + s0;
    bf16_t tmp[16];
#pragma unroll
    for (int i = 0; i < 16; ++i) tmp[i] = Sm[(s0 + i) * 72 + d];
    bf16_t* dst = Vt + ((size_t)(b * 64 + d)) * 2048 + sbase;
    *(uint4*)dst = *(const uint4*)&tmp[0];
    *(uint4*)(dst + 8) = *(const uint4*)&tmp[8];
  }
}

// ---------------- kernel 2: causal flash attention, KV-split across 8 waves --------
// grid (128, 4), block 512 (8 waves). Each block owns 16 q-rows; wave w handles
// KV tiles w, w+8, ... with a private flash state; merged at the end via LDS.
// K/V read directly from global (L2-resident); no barriers in the main loop.
#define NW 8
__global__ __launch_bounds__(512) void attn_kernel(
    const bf16_t* __restrict__ Qb, const bf16_t* __restrict__ Kb,
    const bf16_t* __restrict__ Vt, float* __restrict__ Out) {
  __shared__ alignas(16) char Psm[NW * 2048];   // per-wave P tiles (swizzled)
  __shared__ float accL[NW][16][64];
  __shared__ float mL[NW][16];
  __shared__ float lL[NW][16];

  int b = blockIdx.y;
  int x = blockIdx.x;
  int qt = (b >= 2) ? (127 - x) : x;   // pair heavy+light tiles per CU
  int q0 = qt * 16;
  int tid = threadIdx.x;
  int w = tid >> 6, lane = tid & 63;
  int l15 = lane & 15, g = lane >> 4;
  char* Pw = Psm + w * 2048;

  size_t qrow = (size_t)(b * 2048 + q0 + l15) * 64;
  bf16x8 qf0 = *(const bf16x8*)(Qb + qrow + g * 8);
  bf16x8 qf1 = *(const bf16x8*)(Qb + qrow + 32 + g * 8);

  float m_run[4] = {-1e30f, -1e30f, -1e30f, -1e30f};
  float l_run[4] = {0.f, 0.f, 0.f, 0.f};
  f32x4 acc_o[4] = {};

  int ntiles = (q0 + 79) >> 6;         // ceil((q0+16)/64)
  const bf16_t* kbase = Kb + (size_t)b * 2048 * 64;
  const bf16_t* vbase = Vt + (size_t)b * 64 * 2048;

  for (int t = w; t < ntiles; t += NW) {
    int kv0 = t * 64;
    // S = Q K^T
    f32x4 s[4] = {};
#pragma unroll
    for (int ct = 0; ct < 4; ++ct) {
      const bf16_t* kr = kbase + (size_t)(kv0 + ct * 16 + l15) * 64 + g * 8;
      s[ct] = mfma16(qf0, *(const bf16x8*)kr, s[ct]);
      s[ct] = mfma16(qf1, *(const bf16x8*)(kr + 32), s[ct]);
    }
    if (t == ntiles - 1) {  // diagonal (and ragged-end) tile: causal mask
#pragma unroll
      for (int ct = 0; ct < 4; ++ct)
#pragma unroll
        for (int r = 0; r < 4; ++r) {
          int kg_ = kv0 + ct * 16 + l15;
          int qg_ = q0 + g * 4 + r;
          if (kg_ > qg_) s[ct][r] = -1e30f;
        }
    }

    // online softmax (row = g*4+r, distributed over the 16-lane group)
#pragma unroll
    for (int r = 0; r < 4; ++r) {
      float mx = fmaxf(fmaxf(s[0][r], s[1][r]), fmaxf(s[2][r], s[3][r]));
      mx = fmaxf(mx, __shfl_xor(mx, 1, 64));
      mx = fmaxf(mx, __shfl_xor(mx, 2, 64));
      mx = fmaxf(mx, __shfl_xor(mx, 4, 64));
      mx = fmaxf(mx, __shfl_xor(mx, 8, 64));
      float mnew = fmaxf(m_run[r], mx);
      float scale = exp2f((m_run[r] - mnew) * L2E);
      m_run[r] = mnew;
      float ps = 0.f;
      int qrl = g * 4 + r;
      char* pb = Pw + qrl * 128;
      int swp = (qrl & 7) << 4;
#pragma unroll
      for (int ct = 0; ct < 4; ++ct) {
        float p = exp2f((s[ct][r] - mnew) * L2E);
        ps += p;
        *(bf16_t*)(pb + ((ct * 32 + l15 * 2) ^ swp)) = (bf16_t)p;
      }
      ps += __shfl_xor(ps, 1, 64);
      ps += __shfl_xor(ps, 2, 64);
      ps += __shfl_xor(ps, 4, 64);
      ps += __shfl_xor(ps, 8, 64);
      l_run[r] = l_run[r] * scale + ps;
#pragma unroll
      for (int dt = 0; dt < 4; ++dt) acc_o[dt][r] *= scale;
    }

    // O += P V   (A = P via per-wave LDS transpose, B = V^T straight from global)
    int swpr = (l15 & 7) << 4;
#pragma unroll
    for (int ks = 0; ks < 2; ++ks) {
      bf16x8 pf = *(const bf16x8*)(Pw + l15 * 128 + ((ks * 64 + g * 16) ^ swpr));
#pragma unroll
      for (int dt = 0; dt < 4; ++dt) {
        const bf16_t* vr = vbase + (size_t)(dt * 16 + l15) * 2048 + kv0 + ks * 32 + g * 8;
        acc_o[dt] = mfma16(pf, *(const bf16x8*)vr, acc_o[dt]);
      }
    }
  }

  // publish per-wave partial state
  if (l15 == 0) {
#pragma unroll
    for (int r = 0; r < 4; ++r) {
      mL[w][g * 4 + r] = m_run[r];
      lL[w][g * 4 + r] = l_run[r];
    }
  }
#pragma unroll
  for (int dt = 0; dt < 4; ++dt)
#pragma unroll
    for (int r = 0; r < 4; ++r)
      accL[w][g * 4 + r][dt * 16 + l15] = acc_o[dt][r];
  __syncthreads();

  // merge 8 partials: thread -> (row = tid>>5, d pair = (tid&31)*2)
  int row = tid >> 5, d0 = (tid & 31) * 2;
  float M = -1e30f;
#pragma unroll
  for (int w2 = 0; w2 < NW; ++w2) M = fmaxf(M, mL[w2][row]);
  float L = 0.f, o0 = 0.f, o1 = 0.f;
#pragma unroll
  for (int w2 = 0; w2 < NW; ++w2) {
    float sc = exp2f((mL[w2][row] - M) * L2E);
    L += lL[w2][row] * sc;
    o0 += sc * accL[w2][row][d0];
    o1 += sc * accL[w2][row][d0 + 1];
  }
  float inv = 1.0f / L;
  float2 o2 = {o0 * inv, o1 * inv};
  *(float2*)&Out[(size_t)(b * 2048 + q0 + row) * 64 + d0] = o2;
}

extern "C" void kernel_launch(void* const* d_in, const int* in_sizes, int n_in,
                              void* d_out, int out_size, void* d_ws, size_t ws_size,
                              hipStream_t stream) {
  const float* Xk = (const float*)d_in[0];
  const float* Xv = (const float*)d_in[1];
  const float* Xq = (const float*)d_in[2];
  const float* Wq = (const float*)d_in[3];
  const float* Wk = (const float*)d_in[4];
  const float* Wv = (const float*)d_in[5];
  float* Out = (float*)d_out;

  bf16_t* ws = (bf16_t*)d_ws;
  bf16_t* Qb = ws;                 // [8192][64]   bf16, pre-scaled by 0.125
  bf16_t* Kb = ws + 524288;        // [8192][64]   bf16
  bf16_t* Vt = ws + 1048576;       // [4][64][2048] bf16 (V transposed)
  bf16_t* Wt = ws + 1572864;       // [3][64][1024] bf16 (weights transposed)

  wt_kernel<<<dim3(768), dim3(256), 0, stream>>>(Wq, Wk, Wv, Wt);
  proj_kernel<<<dim3(128, 3), dim3(256), 0, stream>>>(Xq, Xk, Xv, Wt, Qb, Kb, Vt);
  attn_kernel<<<dim3(128, 4), dim3(512), 0, stream>>>(Qb, Kb, Vt, Out);
}

// Round 3
// 70.315 us; speedup vs baseline: 1.7137x; 1.1206x over previous
//
#include <hip/hip_runtime.h>
#include <hip/hip_bf16.h>
#include <stdint.h>

typedef __bf16 bf16_t;
typedef __bf16 bf16x8 __attribute__((ext_vector_type(8)));
typedef float f32x4 __attribute__((ext_vector_type(4)));

#define L2E 1.44269504088896340736f

static __device__ __forceinline__ f32x4 mfma16(bf16x8 a, bf16x8 b, f32x4 c) {
  return __builtin_amdgcn_mfma_f32_16x16x32_bf16(a, b, c, 0, 0, 0);
}

static __device__ __forceinline__ void gload_lds16(const void* g, void* l) {
  __builtin_amdgcn_global_load_lds(
      (const __attribute__((address_space(1))) uint32_t*)g,
      (__attribute__((address_space(3))) uint32_t*)l, 16, 0, 0);
}

// ---------------- kernel 0: weights -> bf16, transposed to [proj][n=64][k=1024] ----
// proj 0 (Q) folds the 1/sqrt(64) scale.
__global__ __launch_bounds__(256) void wt_kernel(const float* __restrict__ Wq,
                                                 const float* __restrict__ Wk,
                                                 const float* __restrict__ Wv,
                                                 bf16_t* __restrict__ Wt) {
  int gid = blockIdx.x * 256 + threadIdx.x;  // 0 .. 196607
  int proj = gid >> 16;
  int rem = gid & 65535;          // = k*64 + n (row-major read, coalesced)
  int k = rem >> 6, n = rem & 63;
  const float* W = (proj == 0) ? Wq : (proj == 1) ? Wk : Wv;
  float v = W[rem];
  if (proj == 0) v *= 0.125f;
  Wt[proj * 65536 + n * 1024 + k] = (bf16_t)v;
}

// ---------------- kernel 1: QKV projection -----------------------------------------
// grid (256, 3), block 128 (2 waves). Block computes 32 rows x 64 cols.
// X staged via global_load_lds (dbuf, swizzled source / swizzled read, rule #21).
__global__ __launch_bounds__(128) void proj_kernel(
    const float* __restrict__ Xq, const float* __restrict__ Xk, const float* __restrict__ Xv,
    const bf16_t* __restrict__ Wt,
    bf16_t* __restrict__ Qb, bf16_t* __restrict__ Kb, bf16_t* __restrict__ Vt) {
  __shared__ alignas(16) float Xs[2][2048];   // 2 x [32 rows][64 k] f32, XOR-swizzled
  __shared__ bf16_t Sm[32 * 72];              // output staging, pad stride 72

  int proj = blockIdx.y;
  const float* X = (proj == 0) ? Xq : (proj == 1) ? Xk : Xv;
  int tid = threadIdx.x;
  int w = tid >> 6, lane = tid & 63;
  int l15 = lane & 15, g = lane >> 4;
  int m0 = blockIdx.x * 32;
  const bf16_t* wt = Wt + proj * 65536;

  // staging geometry: wave w stages tile rows w*16..w*16+15 in 4 rounds of 1KB
  int srow = w * 16 + (lane >> 4);     // + r*4 per round
  int scol = (lane & 15) * 16;         // dest byte within row (pre-swizzle)

  auto stage = [&](int t, int buf) {
    int k0 = t * 64;
    char* lbase = (char*)&Xs[0][0] + buf * 8192 + w * 4096;
#pragma unroll
    for (int r = 0; r < 4; ++r) {
      int R = srow + r * 4;
      int srcb = scol ^ ((R & 7) << 4);                    // inverse-swizzled source
      const char* gsrc = (const char*)(X + (size_t)(m0 + R) * 1024 + k0) + srcb;
      gload_lds16(gsrc, lbase + r * 1024);
    }
  };

  f32x4 acc[4] = {};
  int base_r = w * 16 + l15;
  int swr = (base_r & 7) << 4;

  stage(0, 0);
  int cur = 0;
#pragma unroll 2
  for (int t = 0; t < 16; ++t) {
    __syncthreads();                       // drains stage(t) (vmcnt(0) at barrier)
    if (t < 15) stage(t + 1, cur ^ 1);
    const char* bufp = (const char*)&Xs[0][0] + cur * 8192 + base_r * 256;
    const bf16_t* wk = wt + t * 64;
#pragma unroll
    for (int s = 0; s < 2; ++s) {
      int c0 = s * 128 + g * 32;
      float4 u0 = *(const float4*)(bufp + (c0 ^ swr));
      float4 u1 = *(const float4*)(bufp + ((c0 + 16) ^ swr));
      bf16x8 af;
      af[0] = (bf16_t)u0.x; af[1] = (bf16_t)u0.y; af[2] = (bf16_t)u0.z; af[3] = (bf16_t)u0.w;
      af[4] = (bf16_t)u1.x; af[5] = (bf16_t)u1.y; af[6] = (bf16_t)u1.z; af[7] = (bf16_t)u1.w;
      const bf16_t* wks = wk + s * 32 + g * 8;
#pragma unroll
      for (int ct = 0; ct < 4; ++ct) {
        bf16x8 bfr = *(const bf16x8*)(wks + (ct * 16 + l15) * 1024);
        acc[ct] = mfma16(af, bfr, acc[ct]);
      }
    }
    cur ^= 1;
  }

  // C layout: row = w*16 + g*4 + r, col = ct*16 + l15 -> stage in LDS
#pragma unroll
  for (int ct = 0; ct < 4; ++ct)
#pragma unroll
    for (int r = 0; r < 4; ++r)
      Sm[(w * 16 + g * 4 + r) * 72 + ct * 16 + l15] = (bf16_t)acc[ct][r];
  __syncthreads();

  if (proj < 2) {
    bf16_t* Ob = (proj == 0) ? Qb : Kb;
    int row = tid >> 2, c0 = (tid & 3) * 16;
    uint4 v0 = *(const uint4*)&Sm[row * 72 + c0];
    uint4 v1 = *(const uint4*)&Sm[row * 72 + c0 + 8];
    *(uint4*)&Ob[(size_t)(m0 + row) * 64 + c0] = v0;
    *(uint4*)&Ob[(size_t)(m0 + row) * 64 + c0 + 8] = v1;
  } else {
    int d = tid >> 1, sh = (tid & 1) * 16;
    int b = m0 >> 11;
    int sbase = (m0 & 2047) + sh;
    bf16_t tmp[16];
#pragma unroll
    for (int i = 0; i < 16; ++i) tmp[i] = Sm[(sh + i) * 72 + d];
    bf16_t* dst = Vt + ((size_t)(b * 64 + d)) * 2048 + sbase;
    *(uint4*)dst = *(const uint4*)&tmp[0];
    *(uint4*)(dst + 8) = *(const uint4*)&tmp[8];
  }
}

// ---------------- kernel 2: causal flash attention, KV-split across 8 waves --------
// grid (128, 4), block 512 (8 waves). Each block owns 16 q-rows; wave w handles
// KV tiles w, w+8, ... with a private flash state; merged at the end via LDS.
// K/V read directly from global (L2-resident); no barriers in the main loop.
#define NW 8
__global__ __launch_bounds__(512) void attn_kernel(
    const bf16_t* __restrict__ Qb, const bf16_t* __restrict__ Kb,
    const bf16_t* __restrict__ Vt, float* __restrict__ Out) {
  __shared__ alignas(16) char Psm[NW * 2048];   // per-wave P tiles (swizzled)
  __shared__ float accL[NW][16][64];
  __shared__ float mL[NW][16];
  __shared__ float lL[NW][16];

  int b = blockIdx.y;
  int x = blockIdx.x;
  int qt = (b >= 2) ? (127 - x) : x;   // pair heavy+light tiles per CU
  int q0 = qt * 16;
  int tid = threadIdx.x;
  int w = tid >> 6, lane = tid & 63;
  int l15 = lane & 15, g = lane >> 4;
  char* Pw = Psm + w * 2048;

  size_t qrow = (size_t)(b * 2048 + q0 + l15) * 64;
  bf16x8 qf0 = *(const bf16x8*)(Qb + qrow + g * 8);
  bf16x8 qf1 = *(const bf16x8*)(Qb + qrow + 32 + g * 8);

  float m_run[4] = {-1e30f, -1e30f, -1e30f, -1e30f};
  float l_run[4] = {0.f, 0.f, 0.f, 0.f};
  f32x4 acc_o[4] = {};

  int ntiles = (q0 + 79) >> 6;         // ceil((q0+16)/64)
  const bf16_t* kbase = Kb + (size_t)b * 2048 * 64;
  const bf16_t* vbase = Vt + (size_t)b * 64 * 2048;

  for (int t = w; t < ntiles; t += NW) {
    int kv0 = t * 64;
    // S = Q K^T
    f32x4 s[4] = {};
#pragma unroll
    for (int ct = 0; ct < 4; ++ct) {
      const bf16_t* kr = kbase + (size_t)(kv0 + ct * 16 + l15) * 64 + g * 8;
      s[ct] = mfma16(qf0, *(const bf16x8*)kr, s[ct]);
      s[ct] = mfma16(qf1, *(const bf16x8*)(kr + 32), s[ct]);
    }
    if (t == ntiles - 1) {  // diagonal tile: causal mask
#pragma unroll
      for (int ct = 0; ct < 4; ++ct)
#pragma unroll
        for (int r = 0; r < 4; ++r) {
          int kg_ = kv0 + ct * 16 + l15;
          int qg_ = q0 + g * 4 + r;
          if (kg_ > qg_) s[ct][r] = -1e30f;
        }
    }

    // online softmax (row = g*4+r, distributed over the 16-lane group)
#pragma unroll
    for (int r = 0; r < 4; ++r) {
      float mx = fmaxf(fmaxf(s[0][r], s[1][r]), fmaxf(s[2][r], s[3][r]));
      mx = fmaxf(mx, __shfl_xor(mx, 1, 64));
      mx = fmaxf(mx, __shfl_xor(mx, 2, 64));
      mx = fmaxf(mx, __shfl_xor(mx, 4, 64));
      mx = fmaxf(mx, __shfl_xor(mx, 8, 64));
      float mnew = fmaxf(m_run[r], mx);
      float scale = exp2f((m_run[r] - mnew) * L2E);
      m_run[r] = mnew;
      float ps = 0.f;
      int qrl = g * 4 + r;
      char* pb = Pw + qrl * 128;
      int swp = (qrl & 7) << 4;
#pragma unroll
      for (int ct = 0; ct < 4; ++ct) {
        float p = exp2f((s[ct][r] - mnew) * L2E);
        ps += p;
        *(bf16_t*)(pb + ((ct * 32 + l15 * 2) ^ swp)) = (bf16_t)p;
      }
      ps += __shfl_xor(ps, 1, 64);
      ps += __shfl_xor(ps, 2, 64);
      ps += __shfl_xor(ps, 4, 64);
      ps += __shfl_xor(ps, 8, 64);
      l_run[r] = l_run[r] * scale + ps;
#pragma unroll
      for (int dt = 0; dt < 4; ++dt) acc_o[dt][r] *= scale;
    }

    // O += P V   (A = P via per-wave LDS transpose, B = V^T straight from global)
    int swpr = (l15 & 7) << 4;
#pragma unroll
    for (int ks = 0; ks < 2; ++ks) {
      bf16x8 pf = *(const bf16x8*)(Pw + l15 * 128 + ((ks * 64 + g * 16) ^ swpr));
#pragma unroll
      for (int dt = 0; dt < 4; ++dt) {
        const bf16_t* vr = vbase + (size_t)(dt * 16 + l15) * 2048 + kv0 + ks * 32 + g * 8;
        acc_o[dt] = mfma16(pf, *(const bf16x8*)vr, acc_o[dt]);
      }
    }
  }

  // publish per-wave partial state
  if (l15 == 0) {
#pragma unroll
    for (int r = 0; r < 4; ++r) {
      mL[w][g * 4 + r] = m_run[r];
      lL[w][g * 4 + r] = l_run[r];
    }
  }
#pragma unroll
  for (int dt = 0; dt < 4; ++dt)
#pragma unroll
    for (int r = 0; r < 4; ++r)
      accL[w][g * 4 + r][dt * 16 + l15] = acc_o[dt][r];
  __syncthreads();

  // merge 8 partials: thread -> (row = tid>>5, d pair = (tid&31)*2)
  int row = tid >> 5, d0 = (tid & 31) * 2;
  float M = -1e30f;
#pragma unroll
  for (int w2 = 0; w2 < NW; ++w2) M = fmaxf(M, mL[w2][row]);
  float L = 0.f, o0 = 0.f, o1 = 0.f;
#pragma unroll
  for (int w2 = 0; w2 < NW; ++w2) {
    float sc = exp2f((mL[w2][row] - M) * L2E);
    L += lL[w2][row] * sc;
    o0 += sc * accL[w2][row][d0];
    o1 += sc * accL[w2][row][d0 + 1];
  }
  float inv = 1.0f / L;
  float2 o2 = {o0 * inv, o1 * inv};
  *(float2*)&Out[(size_t)(b * 2048 + q0 + row) * 64 + d0] = o2;
}

extern "C" void kernel_launch(void* const* d_in, const int* in_sizes, int n_in,
                              void* d_out, int out_size, void* d_ws, size_t ws_size,
                              hipStream_t stream) {
  const float* Xk = (const float*)d_in[0];
  const float* Xv = (const float*)d_in[1];
  const float* Xq = (const float*)d_in[2];
  const float* Wq = (const float*)d_in[3];
  const float* Wk = (const float*)d_in[4];
  const float* Wv = (const float*)d_in[5];
  float* Out = (float*)d_out;

  bf16_t* ws = (bf16_t*)d_ws;
  bf16_t* Qb = ws;                 // [8192][64]   bf16, pre-scaled by 0.125
  bf16_t* Kb = ws + 524288;        // [8192][64]   bf16
  bf16_t* Vt = ws + 1048576;       // [4][64][2048] bf16 (V transposed)
  bf16_t* Wt = ws + 1572864;       // [3][64][1024] bf16 (weights transposed)

  wt_kernel<<<dim3(768), dim3(256), 0, stream>>>(Wq, Wk, Wv, Wt);
  proj_kernel<<<dim3(256, 3), dim3(128), 0, stream>>>(Xq, Xk, Xv, Wt, Qb, Kb, Vt);
  attn_kernel<<<dim3(128, 4), dim3(512), 0, stream>>>(Qb, Kb, Vt, Out);
}

// Round 4
// 62.752 us; speedup vs baseline: 1.9202x; 1.1205x over previous
//
#include <hip/hip_runtime.h>
#include <hip/hip_bf16.h>
#include <stdint.h>

typedef __bf16 bf16_t;
typedef __bf16 bf16x8 __attribute__((ext_vector_type(8)));
typedef float f32x4 __attribute__((ext_vector_type(4)));

#define L2E 1.44269504088896340736f
#define VMCNT4 asm volatile("s_waitcnt vmcnt(4)" ::: "memory")
#define VMCNT0 asm volatile("s_waitcnt vmcnt(0)" ::: "memory")

static __device__ __forceinline__ f32x4 mfma16(bf16x8 a, bf16x8 b, f32x4 c) {
  return __builtin_amdgcn_mfma_f32_16x16x32_bf16(a, b, c, 0, 0, 0);
}

static __device__ __forceinline__ void gload_lds16(const void* g, void* l) {
  __builtin_amdgcn_global_load_lds(
      (const __attribute__((address_space(1))) uint32_t*)g,
      (__attribute__((address_space(3))) uint32_t*)l, 16, 0, 0);
}

// ---------------- kernel 0: weights -> bf16, transposed to [proj][n=64][k=1024] ----
// proj 0 (Q) folds the 1/sqrt(64) scale.
__global__ __launch_bounds__(256) void wt_kernel(const float* __restrict__ Wq,
                                                 const float* __restrict__ Wk,
                                                 const float* __restrict__ Wv,
                                                 bf16_t* __restrict__ Wt) {
  int gid = blockIdx.x * 256 + threadIdx.x;  // 0 .. 196607
  int proj = gid >> 16;
  int rem = gid & 65535;          // = k*64 + n (row-major read, coalesced)
  int k = rem >> 6, n = rem & 63;
  const float* W = (proj == 0) ? Wq : (proj == 1) ? Wk : Wv;
  float v = W[rem];
  if (proj == 0) v *= 0.125f;
  Wt[proj * 65536 + n * 1024 + k] = (bf16_t)v;
}

// ---------------- kernel 1: QKV projection, K-split across waves -------------------
// grid (512, 3), block 256 (4 waves). Block computes 16 rows x 64 cols.
// Wave w owns k-slice [w*256, w*256+256) as 4 subtiles of 64; partials merged in LDS.
// Staging is WAVE-PRIVATE: global_load_lds dbuf + counted vmcnt, zero main-loop
// barriers. Swizzle per rule #21: linear LDS dest, inverse-swizzled source, swizzled
// read (chunk ^ (row&7)<<5 -> 4-way instead of 16-way conflict).
__global__ __launch_bounds__(256) void proj_kernel(
    const float* __restrict__ Xq, const float* __restrict__ Xk, const float* __restrict__ Xv,
    const bf16_t* __restrict__ Wt,
    bf16_t* __restrict__ Qb, bf16_t* __restrict__ Kb, bf16_t* __restrict__ Vt) {
  __shared__ alignas(16) float Xs[4][2][1024];  // [wave][buf][16 rows * 64 k] f32
  __shared__ bf16_t Sm[16 * 72];                // V output transpose staging

  int proj = blockIdx.y;
  const float* X = (proj == 0) ? Xq : (proj == 1) ? Xk : Xv;
  int tid = threadIdx.x;
  int w = tid >> 6, lane = tid & 63;
  int l15 = lane & 15, g = lane >> 4;
  int m0 = blockIdx.x * 16;
  const bf16_t* wt = Wt + proj * 65536 + w * 256;  // wave's k-slice base

  const char* Xb = (const char*)X;
  int sr4 = lane >> 4;           // row-within-quad for staging
  int sc = (lane & 15) * 16;     // 16B chunk within the 256B row segment

  auto stage = [&](int t, int buf) {
    char* lbase = (char*)&Xs[w][buf][0];
    int kb = (w * 256 + t * 64) * 4;   // byte offset of k0 within an X row
#pragma unroll
    for (int i = 0; i < 4; ++i) {
      int R = i * 4 + sr4;
      const char* gsrc = Xb + (size_t)(m0 + R) * 4096 + kb + (sc ^ ((R & 7) << 5));
      gload_lds16(gsrc, lbase + i * 1024);
    }
  };

  f32x4 acc[4] = {};
  int swz = (l15 & 7) << 5;

  auto compute = [&](int t, int buf) {
    const char* bufp = (const char*)&Xs[w][buf][0] + l15 * 256;
    const bf16_t* wk = wt + t * 64 + g * 8;
#pragma unroll
    for (int kk = 0; kk < 2; ++kk) {
      const char* p = bufp + ((kk * 128 + g * 32) ^ swz);
      float4 u0 = *(const float4*)p;
      float4 u1 = *(const float4*)(p + 16);
      bf16x8 af;
      af[0] = (bf16_t)u0.x; af[1] = (bf16_t)u0.y; af[2] = (bf16_t)u0.z; af[3] = (bf16_t)u0.w;
      af[4] = (bf16_t)u1.x; af[5] = (bf16_t)u1.y; af[6] = (bf16_t)u1.z; af[7] = (bf16_t)u1.w;
      const bf16_t* wks = wk + kk * 32;
#pragma unroll
      for (int ct = 0; ct < 4; ++ct)
        acc[ct] = mfma16(af, *(const bf16x8*)(wks + (ct * 16 + l15) * 1024), acc[ct]);
    }
  };

  stage(0, 0);
  stage(1, 1);
  VMCNT4; compute(0, 0);
  __builtin_amdgcn_sched_barrier(0);
  stage(2, 0);
  VMCNT4; compute(1, 1);
  __builtin_amdgcn_sched_barrier(0);
  stage(3, 1);
  VMCNT4; compute(2, 0);
  VMCNT0; compute(3, 1);

  // ---- merge the 4 per-wave K-partials (overlay Ms on Xs) ----
  __syncthreads();                      // all waves done with their private Xs
  float* Ms = (float*)&Xs[0][0][0];     // [wave][16 rows][64 cols] f32
#pragma unroll
  for (int ct = 0; ct < 4; ++ct)
#pragma unroll
    for (int r = 0; r < 4; ++r)
      Ms[w * 1024 + (g * 4 + r) * 64 + ct * 16 + l15] = acc[ct][r];
  __syncthreads();

  int row = tid >> 4, c0 = (tid & 15) * 4;
  f32x4 s = *(const f32x4*)&Ms[row * 64 + c0];
#pragma unroll
  for (int w2 = 1; w2 < 4; ++w2) {
    f32x4 q = *(const f32x4*)&Ms[w2 * 1024 + row * 64 + c0];
    s[0] += q[0]; s[1] += q[1]; s[2] += q[2]; s[3] += q[3];
  }

  if (proj < 2) {
    bf16_t* Ob = (proj == 0) ? Qb : Kb;
    bf16_t o4[4] = {(bf16_t)s[0], (bf16_t)s[1], (bf16_t)s[2], (bf16_t)s[3]};
    *(uint2*)&Ob[(size_t)(m0 + row) * 64 + c0] = *(const uint2*)o4;
  } else {
#pragma unroll
    for (int i = 0; i < 4; ++i) Sm[row * 72 + c0 + i] = (bf16_t)s[i];
    __syncthreads();
    if (tid < 128) {
      int d = tid >> 1, half = tid & 1;
      int b = m0 >> 11;
      int sbase = (m0 & 2047) + half * 8;
      bf16_t tmp[8];
#pragma unroll
      for (int i = 0; i < 8; ++i) tmp[i] = Sm[(half * 8 + i) * 72 + d];
      *(uint4*)(Vt + ((size_t)(b * 64 + d)) * 2048 + sbase) = *(const uint4*)tmp;
    }
  }
}

// ---------------- kernel 2: causal flash attention, KV-split across 8 waves --------
// grid (128, 4), block 512 (8 waves). Each block owns 16 q-rows; wave w handles
// KV tiles w, w+8, ... with a private flash state; merged at the end via LDS.
// K/V read directly from global (L2-resident); no barriers in the main loop.
#define NW 8
__global__ __launch_bounds__(512) void attn_kernel(
    const bf16_t* __restrict__ Qb, const bf16_t* __restrict__ Kb,
    const bf16_t* __restrict__ Vt, float* __restrict__ Out) {
  __shared__ alignas(16) char Psm[NW * 2048];   // per-wave P tiles (swizzled)
  __shared__ float accL[NW][16][64];
  __shared__ float mL[NW][16];
  __shared__ float lL[NW][16];

  int b = blockIdx.y;
  int x = blockIdx.x;
  int qt = (b >= 2) ? (127 - x) : x;   // pair heavy+light tiles per CU
  int q0 = qt * 16;
  int tid = threadIdx.x;
  int w = tid >> 6, lane = tid & 63;
  int l15 = lane & 15, g = lane >> 4;
  char* Pw = Psm + w * 2048;

  size_t qrow = (size_t)(b * 2048 + q0 + l15) * 64;
  bf16x8 qf0 = *(const bf16x8*)(Qb + qrow + g * 8);
  bf16x8 qf1 = *(const bf16x8*)(Qb + qrow + 32 + g * 8);

  float m_run[4] = {-1e30f, -1e30f, -1e30f, -1e30f};
  float l_run[4] = {0.f, 0.f, 0.f, 0.f};
  f32x4 acc_o[4] = {};

  int ntiles = (q0 + 79) >> 6;         // ceil((q0+16)/64)
  const bf16_t* kbase = Kb + (size_t)b * 2048 * 64;
  const bf16_t* vbase = Vt + (size_t)b * 64 * 2048;

  for (int t = w; t < ntiles; t += NW) {
    int kv0 = t * 64;
    // S = Q K^T
    f32x4 s[4] = {};
#pragma unroll
    for (int ct = 0; ct < 4; ++ct) {
      const bf16_t* kr = kbase + (size_t)(kv0 + ct * 16 + l15) * 64 + g * 8;
      s[ct] = mfma16(qf0, *(const bf16x8*)kr, s[ct]);
      s[ct] = mfma16(qf1, *(const bf16x8*)(kr + 32), s[ct]);
    }
    if (t == ntiles - 1) {  // diagonal tile: causal mask
#pragma unroll
      for (int ct = 0; ct < 4; ++ct)
#pragma unroll
        for (int r = 0; r < 4; ++r) {
          int kg_ = kv0 + ct * 16 + l15;
          int qg_ = q0 + g * 4 + r;
          if (kg_ > qg_) s[ct][r] = -1e30f;
        }
    }

    // online softmax (row = g*4+r, distributed over the 16-lane group)
#pragma unroll
    for (int r = 0; r < 4; ++r) {
      float mx = fmaxf(fmaxf(s[0][r], s[1][r]), fmaxf(s[2][r], s[3][r]));
      mx = fmaxf(mx, __shfl_xor(mx, 1, 64));
      mx = fmaxf(mx, __shfl_xor(mx, 2, 64));
      mx = fmaxf(mx, __shfl_xor(mx, 4, 64));
      mx = fmaxf(mx, __shfl_xor(mx, 8, 64));
      float mnew = fmaxf(m_run[r], mx);
      float scale = exp2f((m_run[r] - mnew) * L2E);
      m_run[r] = mnew;
      float ps = 0.f;
      int qrl = g * 4 + r;
      char* pb = Pw + qrl * 128;
      int swp = (qrl & 7) << 4;
#pragma unroll
      for (int ct = 0; ct < 4; ++ct) {
        float p = exp2f((s[ct][r] - mnew) * L2E);
        ps += p;
        *(bf16_t*)(pb + ((ct * 32 + l15 * 2) ^ swp)) = (bf16_t)p;
      }
      ps += __shfl_xor(ps, 1, 64);
      ps += __shfl_xor(ps, 2, 64);
      ps += __shfl_xor(ps, 4, 64);
      ps += __shfl_xor(ps, 8, 64);
      l_run[r] = l_run[r] * scale + ps;
#pragma unroll
      for (int dt = 0; dt < 4; ++dt) acc_o[dt][r] *= scale;
    }

    // O += P V   (A = P via per-wave LDS transpose, B = V^T straight from global)
    int swpr = (l15 & 7) << 4;
#pragma unroll
    for (int ks = 0; ks < 2; ++ks) {
      bf16x8 pf = *(const bf16x8*)(Pw + l15 * 128 + ((ks * 64 + g * 16) ^ swpr));
#pragma unroll
      for (int dt = 0; dt < 4; ++dt) {
        const bf16_t* vr = vbase + (size_t)(dt * 16 + l15) * 2048 + kv0 + ks * 32 + g * 8;
        acc_o[dt] = mfma16(pf, *(const bf16x8*)vr, acc_o[dt]);
      }
    }
  }

  // publish per-wave partial state
  if (l15 == 0) {
#pragma unroll
    for (int r = 0; r < 4; ++r) {
      mL[w][g * 4 + r] = m_run[r];
      lL[w][g * 4 + r] = l_run[r];
    }
  }
#pragma unroll
  for (int dt = 0; dt < 4; ++dt)
#pragma unroll
    for (int r = 0; r < 4; ++r)
      accL[w][g * 4 + r][dt * 16 + l15] = acc_o[dt][r];
  __syncthreads();

  // merge 8 partials: thread -> (row = tid>>5, d pair = (tid&31)*2)
  int row = tid >> 5, d0 = (tid & 31) * 2;
  float M = -1e30f;
#pragma unroll
  for (int w2 = 0; w2 < NW; ++w2) M = fmaxf(M, mL[w2][row]);
  float L = 0.f, o0 = 0.f, o1 = 0.f;
#pragma unroll
  for (int w2 = 0; w2 < NW; ++w2) {
    float sc = exp2f((mL[w2][row] - M) * L2E);
    L += lL[w2][row] * sc;
    o0 += sc * accL[w2][row][d0];
    o1 += sc * accL[w2][row][d0 + 1];
  }
  float inv = 1.0f / L;
  float2 o2 = {o0 * inv, o1 * inv};
  *(float2*)&Out[(size_t)(b * 2048 + q0 + row) * 64 + d0] = o2;
}

extern "C" void kernel_launch(void* const* d_in, const int* in_sizes, int n_in,
                              void* d_out, int out_size, void* d_ws, size_t ws_size,
                              hipStream_t stream) {
  const float* Xk = (const float*)d_in[0];
  const float* Xv = (const float*)d_in[1];
  const float* Xq = (const float*)d_in[2];
  const float* Wq = (const float*)d_in[3];
  const float* Wk = (const float*)d_in[4];
  const float* Wv = (const float*)d_in[5];
  float* Out = (float*)d_out;

  bf16_t* ws = (bf16_t*)d_ws;
  bf16_t* Qb = ws;                 // [8192][64]   bf16, pre-scaled by 0.125
  bf16_t* Kb = ws + 524288;        // [8192][64]   bf16
  bf16_t* Vt = ws + 1048576;       // [4][64][2048] bf16 (V transposed)
  bf16_t* Wt = ws + 1572864;       // [3][64][1024] bf16 (weights transposed)

  wt_kernel<<<dim3(768), dim3(256), 0, stream>>>(Wq, Wk, Wv, Wt);
  proj_kernel<<<dim3(512, 3), dim3(256), 0, stream>>>(Xq, Xk, Xv, Wt, Qb, Kb, Vt);
  attn_kernel<<<dim3(128, 4), dim3(512), 0, stream>>>(Qb, Kb, Vt, Out);
}

// Round 5
// 53.240 us; speedup vs baseline: 2.2633x; 1.1787x over previous
//
#include <hip/hip_runtime.h>
#include <hip/hip_bf16.h>
#include <stdint.h>

typedef __bf16 bf16_t;
typedef __bf16 bf16x8 __attribute__((ext_vector_type(8)));
typedef float f32x4 __attribute__((ext_vector_type(4)));

#define L2E 1.44269504088896340736f

static __device__ __forceinline__ f32x4 mfma16(bf16x8 a, bf16x8 b, f32x4 c) {
  return __builtin_amdgcn_mfma_f32_16x16x32_bf16(a, b, c, 0, 0, 0);
}

static __device__ __forceinline__ void gload_lds16(const void* g, void* l) {
  __builtin_amdgcn_global_load_lds(
      (const __attribute__((address_space(1))) uint32_t*)g,
      (__attribute__((address_space(3))) uint32_t*)l, 16, 0, 0);
}

static __device__ __forceinline__ float bf2f(uint16_t u) {
  union { uint32_t i; float f; } v; v.i = (uint32_t)u << 16; return v.f;
}

// ---------------- kernel 0: weights -> bf16, transposed to [proj][n=64][k=1024] ----
// proj 0 (Q) folds the 1/sqrt(64) scale.
__global__ __launch_bounds__(256) void wt_kernel(const float* __restrict__ Wq,
                                                 const float* __restrict__ Wk,
                                                 const float* __restrict__ Wv,
                                                 bf16_t* __restrict__ Wt) {
  int gid = blockIdx.x * 256 + threadIdx.x;  // 0 .. 196607
  int proj = gid >> 16;
  int rem = gid & 65535;          // = k*64 + n (row-major read, coalesced)
  int k = rem >> 6, n = rem & 63;
  const float* W = (proj == 0) ? Wq : (proj == 1) ? Wk : Wv;
  float v = W[rem];
  if (proj == 0) v *= 0.125f;
  Wt[proj * 65536 + n * 1024 + k] = (bf16_t)v;
}

// ---------------- kernel 1: QKV projection, W-in-registers, K-split 8 waves --------
// grid 256 blocks x 512 thr (8 waves), 1 block/CU. Block handles 6 tiles of 16 rows
// over the flat row space [3 proj][8192 rows]. Wave w owns k-slice [128w,128w+128):
// its W fragments (64 VGPR) load once per block via coalesced gload_lds->LDS bounce.
// X reg-staged (float4 -> cvt bf16 -> swizzled ds_write), cross-tile prefetch.
// Per tile: 8-way k-merge via bf16 LDS, coalesced out (V transposed via overlay).
__global__ __launch_bounds__(512) void proj_kernel(
    const float* __restrict__ Xq, const float* __restrict__ Xk, const float* __restrict__ Xv,
    const bf16_t* __restrict__ Wt,
    bf16_t* __restrict__ Qb, bf16_t* __restrict__ Kb, bf16_t* __restrict__ Vt) {
  __shared__ alignas(16) char Xl[8 * 4096];        // per-wave dbuf: 2 x 2KB bf16 tiles
  __shared__ alignas(16) bf16_t Msm[8][16][64];    // merge partials (bf16), 16 KB

  int tid = threadIdx.x;
  int w = tid >> 6, lane = tid & 63;
  int l15 = lane & 15, g = lane >> 4;
  char* myx = Xl + w * 4096;
  int kw = w;                                      // k-slice id

  bf16x8 Wf[4][4];                                 // [ct][s2] = W[n=ct*16+l15][k=kw*128+s2*32+g*8..]

  auto loadW = [&](int p) {
    const char* wb = (const char*)Wt + (size_t)p * 131072 + (size_t)kw * 256;
#pragma unroll
    for (int ct = 0; ct < 4; ++ct) {
      // stage chunk [16 n][128 k] bf16 = 4KB, linear LDS dest, inverse-swz source
#pragma unroll
      for (int i = 0; i < 4; ++i) {
        int n = i * 4 + (lane >> 4);
        int srcb = ((lane & 15) * 16) ^ ((n & 7) << 4);
        gload_lds16(wb + (size_t)(ct * 16 + n) * 2048 + srcb, myx + i * 1024);
      }
      asm volatile("s_waitcnt vmcnt(0)" ::: "memory");
      __builtin_amdgcn_sched_barrier(0);
#pragma unroll
      for (int s2 = 0; s2 < 4; ++s2)
        Wf[ct][s2] = *(const bf16x8*)(myx + l15 * 256 + ((s2 * 64 + g * 16) ^ ((l15 & 7) << 4)));
      asm volatile("s_waitcnt lgkmcnt(0)" ::: "memory");
      __builtin_amdgcn_sched_barrier(0);
    }
  };

  f32x4 acc[4] = {};
  float4 xA[4], xB[4];

  auto issueX = [&](int t, int sub, float4* xr) {
    int p = t >> 9, lt = t & 511;
    const float* X = (p == 0) ? Xq : (p == 1) ? Xk : Xv;
    const float* base = X + (size_t)lt * 16384 + kw * 128 + sub * 64 + (lane & 15) * 4;
#pragma unroll
    for (int i = 0; i < 4; ++i)
      xr[i] = *(const float4*)(base + ((lane >> 4) + 4 * i) * 1024);
  };

  auto writeX = [&](const float4* xr, int sub) {
    char* buf = myx + sub * 2048;
#pragma unroll
    for (int i = 0; i < 4; ++i) {
      int rw = (lane >> 4) + 4 * i;
      bf16_t t4[4] = {(bf16_t)xr[i].x, (bf16_t)xr[i].y, (bf16_t)xr[i].z, (bf16_t)xr[i].w};
      *(uint2*)(buf + rw * 128 + (((lane & 15) * 8) ^ ((rw & 7) << 4))) = *(const uint2*)t4;
    }
    asm volatile("s_waitcnt lgkmcnt(0)" ::: "memory");
    __builtin_amdgcn_sched_barrier(0);
  };

  auto computeX = [&](int sub) {
    const char* buf = myx + sub * 2048;
#pragma unroll
    for (int ks = 0; ks < 2; ++ks) {
      bf16x8 af = *(const bf16x8*)(buf + l15 * 128 + ((ks * 64 + g * 16) ^ ((l15 & 7) << 4)));
#pragma unroll
      for (int ct = 0; ct < 4; ++ct)
        acc[ct] = mfma16(af, Wf[ct][sub * 2 + ks], acc[ct]);
    }
  };

  int t0 = blockIdx.x * 6;
  int cur_p = t0 >> 9;
  loadW(cur_p);
  issueX(t0, 0, xA);

#pragma unroll 1
  for (int T = 0; T < 6; ++T) {
    int t = t0 + T;
    int p = t >> 9, lt = t & 511;
    if (p != cur_p) { loadW(p); cur_p = p; }
    issueX(t, 1, xB);
    writeX(xA, 0);
    computeX(0);
    if (T < 5) issueX(t + 1, 0, xA);
    writeX(xB, 1);
    computeX(1);

    // ---- 8-way k-merge + output ----
#pragma unroll
    for (int ct = 0; ct < 4; ++ct)
#pragma unroll
      for (int r = 0; r < 4; ++r)
        Msm[w][g * 4 + r][ct * 16 + l15] = (bf16_t)acc[ct][r];
#pragma unroll
    for (int ct = 0; ct < 4; ++ct) acc[ct] = (f32x4){0.f, 0.f, 0.f, 0.f};
    __syncthreads();

    int row = tid >> 5, c0 = (tid & 31) * 2;
    float s0 = 0.f, s1 = 0.f;
#pragma unroll
    for (int w2 = 0; w2 < 8; ++w2) {
      uint32_t u = *(const uint32_t*)&Msm[w2][row][c0];
      s0 += bf2f((uint16_t)u);
      s1 += bf2f((uint16_t)(u >> 16));
    }

    if (p < 2) {
      bf16_t* Ob = (p == 0) ? Qb : Kb;
      bf16_t o2[2] = {(bf16_t)s0, (bf16_t)s1};
      *(uint32_t*)&Ob[(size_t)(lt * 16 + row) * 64 + c0] = *(const uint32_t*)o2;
      __syncthreads();                       // protect Msm before next tile's writes
    } else {
      __syncthreads();                       // reduce-reads done -> overlay allowed
      bf16_t* Vsm = (bf16_t*)&Msm[0][0][0];  // [16 s][64 d], stride 72
      bf16_t o2[2] = {(bf16_t)s0, (bf16_t)s1};
      *(uint32_t*)&Vsm[row * 72 + c0] = *(const uint32_t*)o2;
      __syncthreads();
      if (tid < 128) {
        int d = tid >> 1, h = tid & 1;
        int b = lt >> 7;
        int s_ = (lt & 127) * 16 + h * 8;
        bf16_t tmp[8];
#pragma unroll
        for (int i = 0; i < 8; ++i) tmp[i] = Vsm[(h * 8 + i) * 72 + d];
        *(uint4*)(Vt + ((size_t)(b * 64 + d)) * 2048 + s_) = *(const uint4*)tmp;
      }
      __syncthreads();
    }
  }
}

// ---------------- kernel 2: causal flash attention, KV-split across 8 waves --------
// grid (128, 4), block 512 (8 waves). Each block owns 16 q-rows; wave w handles
// KV tiles w, w+8, ... with a private flash state; merged at the end via LDS.
// K/V read directly from global (L2-resident); no barriers in the main loop.
#define NW 8
__global__ __launch_bounds__(512) void attn_kernel(
    const bf16_t* __restrict__ Qb, const bf16_t* __restrict__ Kb,
    const bf16_t* __restrict__ Vt, float* __restrict__ Out) {
  __shared__ alignas(16) char Psm[NW * 2048];   // per-wave P tiles (swizzled)
  __shared__ float accL[NW][16][64];
  __shared__ float mL[NW][16];
  __shared__ float lL[NW][16];

  int b = blockIdx.y;
  int x = blockIdx.x;
  int qt = (b >= 2) ? (127 - x) : x;   // pair heavy+light tiles per CU
  int q0 = qt * 16;
  int tid = threadIdx.x;
  int w = tid >> 6, lane = tid & 63;
  int l15 = lane & 15, g = lane >> 4;
  char* Pw = Psm + w * 2048;

  size_t qrow = (size_t)(b * 2048 + q0 + l15) * 64;
  bf16x8 qf0 = *(const bf16x8*)(Qb + qrow + g * 8);
  bf16x8 qf1 = *(const bf16x8*)(Qb + qrow + 32 + g * 8);

  float m_run[4] = {-1e30f, -1e30f, -1e30f, -1e30f};
  float l_run[4] = {0.f, 0.f, 0.f, 0.f};
  f32x4 acc_o[4] = {};

  int ntiles = (q0 + 79) >> 6;         // ceil((q0+16)/64)
  const bf16_t* kbase = Kb + (size_t)b * 2048 * 64;
  const bf16_t* vbase = Vt + (size_t)b * 64 * 2048;

  for (int t = w; t < ntiles; t += NW) {
    int kv0 = t * 64;
    // S = Q K^T
    f32x4 s[4] = {};
#pragma unroll
    for (int ct = 0; ct < 4; ++ct) {
      const bf16_t* kr = kbase + (size_t)(kv0 + ct * 16 + l15) * 64 + g * 8;
      s[ct] = mfma16(qf0, *(const bf16x8*)kr, s[ct]);
      s[ct] = mfma16(qf1, *(const bf16x8*)(kr + 32), s[ct]);
    }
    if (t == ntiles - 1) {  // diagonal tile: causal mask
#pragma unroll
      for (int ct = 0; ct < 4; ++ct)
#pragma unroll
        for (int r = 0; r < 4; ++r) {
          int kg_ = kv0 + ct * 16 + l15;
          int qg_ = q0 + g * 4 + r;
          if (kg_ > qg_) s[ct][r] = -1e30f;
        }
    }

    // online softmax (row = g*4+r, distributed over the 16-lane group)
#pragma unroll
    for (int r = 0; r < 4; ++r) {
      float mx = fmaxf(fmaxf(s[0][r], s[1][r]), fmaxf(s[2][r], s[3][r]));
      mx = fmaxf(mx, __shfl_xor(mx, 1, 64));
      mx = fmaxf(mx, __shfl_xor(mx, 2, 64));
      mx = fmaxf(mx, __shfl_xor(mx, 4, 64));
      mx = fmaxf(mx, __shfl_xor(mx, 8, 64));
      float mnew = fmaxf(m_run[r], mx);
      float scale = exp2f((m_run[r] - mnew) * L2E);
      m_run[r] = mnew;
      float ps = 0.f;
      int qrl = g * 4 + r;
      char* pb = Pw + qrl * 128;
      int swp = (qrl & 7) << 4;
#pragma unroll
      for (int ct = 0; ct < 4; ++ct) {
        float p = exp2f((s[ct][r] - mnew) * L2E);
        ps += p;
        *(bf16_t*)(pb + ((ct * 32 + l15 * 2) ^ swp)) = (bf16_t)p;
      }
      ps += __shfl_xor(ps, 1, 64);
      ps += __shfl_xor(ps, 2, 64);
      ps += __shfl_xor(ps, 4, 64);
      ps += __shfl_xor(ps, 8, 64);
      l_run[r] = l_run[r] * scale + ps;
#pragma unroll
      for (int dt = 0; dt < 4; ++dt) acc_o[dt][r] *= scale;
    }

    // O += P V   (A = P via per-wave LDS transpose, B = V^T straight from global)
    int swpr = (l15 & 7) << 4;
#pragma unroll
    for (int ks = 0; ks < 2; ++ks) {
      bf16x8 pf = *(const bf16x8*)(Pw + l15 * 128 + ((ks * 64 + g * 16) ^ swpr));
#pragma unroll
      for (int dt = 0; dt < 4; ++dt) {
        const bf16_t* vr = vbase + (size_t)(dt * 16 + l15) * 2048 + kv0 + ks * 32 + g * 8;
        acc_o[dt] = mfma16(pf, *(const bf16x8*)vr, acc_o[dt]);
      }
    }
  }

  // publish per-wave partial state
  if (l15 == 0) {
#pragma unroll
    for (int r = 0; r < 4; ++r) {
      mL[w][g * 4 + r] = m_run[r];
      lL[w][g * 4 + r] = l_run[r];
    }
  }
#pragma unroll
  for (int dt = 0; dt < 4; ++dt)
#pragma unroll
    for (int r = 0; r < 4; ++r)
      accL[w][g * 4 + r][dt * 16 + l15] = acc_o[dt][r];
  __syncthreads();

  // merge 8 partials: thread -> (row = tid>>5, d pair = (tid&31)*2)
  int row = tid >> 5, d0 = (tid & 31) * 2;
  float M = -1e30f;
#pragma unroll
  for (int w2 = 0; w2 < NW; ++w2) M = fmaxf(M, mL[w2][row]);
  float L = 0.f, o0 = 0.f, o1 = 0.f;
#pragma unroll
  for (int w2 = 0; w2 < NW; ++w2) {
    float sc = exp2f((mL[w2][row] - M) * L2E);
    L += lL[w2][row] * sc;
    o0 += sc * accL[w2][row][d0];
    o1 += sc * accL[w2][row][d0 + 1];
  }
  float inv = 1.0f / L;
  float2 o2 = {o0 * inv, o1 * inv};
  *(float2*)&Out[(size_t)(b * 2048 + q0 + row) * 64 + d0] = o2;
}

extern "C" void kernel_launch(void* const* d_in, const int* in_sizes, int n_in,
                              void* d_out, int out_size, void* d_ws, size_t ws_size,
                              hipStream_t stream) {
  const float* Xk = (const float*)d_in[0];
  const float* Xv = (const float*)d_in[1];
  const float* Xq = (const float*)d_in[2];
  const float* Wq = (const float*)d_in[3];
  const float* Wk = (const float*)d_in[4];
  const float* Wv = (const float*)d_in[5];
  float* Out = (float*)d_out;

  bf16_t* ws = (bf16_t*)d_ws;
  bf16_t* Qb = ws;                 // [8192][64]   bf16, pre-scaled by 0.125
  bf16_t* Kb = ws + 524288;        // [8192][64]   bf16
  bf16_t* Vt = ws + 1048576;       // [4][64][2048] bf16 (V transposed)
  bf16_t* Wt = ws + 1572864;       // [3][64][1024] bf16 (weights transposed)

  wt_kernel<<<dim3(768), dim3(256), 0, stream>>>(Wq, Wk, Wv, Wt);
  proj_kernel<<<dim3(256), dim3(512), 0, stream>>>(Xq, Xk, Xv, Wt, Qb, Kb, Vt);
  attn_kernel<<<dim3(128, 4), dim3(512), 0, stream>>>(Qb, Kb, Vt, Out);
}

// Round 6
// 52.864 us; speedup vs baseline: 2.2794x; 1.0071x over previous
//
#include <hip/hip_runtime.h>
#include <hip/hip_bf16.h>
#include <stdint.h>

typedef __bf16 bf16_t;
typedef __bf16 bf16x8 __attribute__((ext_vector_type(8)));
typedef float f32x4 __attribute__((ext_vector_type(4)));

#define L2E 1.44269504088896340736f

static __device__ __forceinline__ f32x4 mfma16(bf16x8 a, bf16x8 b, f32x4 c) {
  return __builtin_amdgcn_mfma_f32_16x16x32_bf16(a, b, c, 0, 0, 0);
}

static __device__ __forceinline__ void gload_lds16(const void* g, void* l) {
  __builtin_amdgcn_global_load_lds(
      (const __attribute__((address_space(1))) uint32_t*)g,
      (__attribute__((address_space(3))) uint32_t*)l, 16, 0, 0);
}

static __device__ __forceinline__ float bf2f(uint16_t u) {
  union { uint32_t i; float f; } v; v.i = (uint32_t)u << 16; return v.f;
}

// ---------------- kernel 0: weights -> bf16, transposed to [proj][n=64][k=1024] ----
// proj 0 (Q) folds the 1/sqrt(64) scale.
__global__ __launch_bounds__(256) void wt_kernel(const float* __restrict__ Wq,
                                                 const float* __restrict__ Wk,
                                                 const float* __restrict__ Wv,
                                                 bf16_t* __restrict__ Wt) {
  int gid = blockIdx.x * 256 + threadIdx.x;  // 0 .. 196607
  int proj = gid >> 16;
  int rem = gid & 65535;          // = k*64 + n (row-major read, coalesced)
  int k = rem >> 6, n = rem & 63;
  const float* W = (proj == 0) ? Wq : (proj == 1) ? Wk : Wv;
  float v = W[rem];
  if (proj == 0) v *= 0.125f;
  Wt[proj * 65536 + n * 1024 + k] = (bf16_t)v;
}

// ---------------- kernel 1: QKV projection, W-in-registers, K-split 8 waves --------
// grid 512 blocks x 512 thr (8 waves), 2 blocks/CU (LDS 48KB). Block handles 3 tiles
// of 16 rows over the flat row space [3 proj][8192 rows]. Wave w owns k-slice
// [128w,128w+128): W fragments (64 VGPR) load once per block via gload_lds bounce.
// X reg-staged (float4 -> cvt bf16 -> swizzled ds_write), cross-tile prefetch.
// Per tile: 8-way k-merge via bf16 LDS, coalesced out (V transposed via overlay).
__global__ __launch_bounds__(512) void proj_kernel(
    const float* __restrict__ Xq, const float* __restrict__ Xk, const float* __restrict__ Xv,
    const bf16_t* __restrict__ Wt,
    bf16_t* __restrict__ Qb, bf16_t* __restrict__ Kb, bf16_t* __restrict__ Vt) {
  __shared__ alignas(16) char Xl[8 * 4096];        // per-wave dbuf: 2 x 2KB bf16 tiles
  __shared__ alignas(16) bf16_t Msm[8][16][64];    // merge partials (bf16), 16 KB

  int tid = threadIdx.x;
  int w = tid >> 6, lane = tid & 63;
  int l15 = lane & 15, g = lane >> 4;
  char* myx = Xl + w * 4096;
  int kw = w;                                      // k-slice id

  bf16x8 Wf[4][4];                                 // [ct][s2]

  auto loadW = [&](int p) {
    const char* wb = (const char*)Wt + (size_t)p * 131072 + (size_t)kw * 256;
#pragma unroll
    for (int ct = 0; ct < 4; ++ct) {
#pragma unroll
      for (int i = 0; i < 4; ++i) {
        int n = i * 4 + (lane >> 4);
        int srcb = ((lane & 15) * 16) ^ ((n & 7) << 4);
        gload_lds16(wb + (size_t)(ct * 16 + n) * 2048 + srcb, myx + i * 1024);
      }
      asm volatile("s_waitcnt vmcnt(0)" ::: "memory");
      __builtin_amdgcn_sched_barrier(0);
#pragma unroll
      for (int s2 = 0; s2 < 4; ++s2)
        Wf[ct][s2] = *(const bf16x8*)(myx + l15 * 256 + ((s2 * 64 + g * 16) ^ ((l15 & 7) << 4)));
      asm volatile("s_waitcnt lgkmcnt(0)" ::: "memory");
      __builtin_amdgcn_sched_barrier(0);
    }
  };

  f32x4 acc[4] = {};
  float4 xA[4], xB[4];

  auto issueX = [&](int t, int sub, float4* xr) {
    int p = t >> 9, lt = t & 511;
    const float* X = (p == 0) ? Xq : (p == 1) ? Xk : Xv;
    const float* base = X + (size_t)lt * 16384 + kw * 128 + sub * 64 + (lane & 15) * 4;
#pragma unroll
    for (int i = 0; i < 4; ++i)
      xr[i] = *(const float4*)(base + ((lane >> 4) + 4 * i) * 1024);
  };

  auto writeX = [&](const float4* xr, int sub) {
    char* buf = myx + sub * 2048;
#pragma unroll
    for (int i = 0; i < 4; ++i) {
      int rw = (lane >> 4) + 4 * i;
      bf16_t t4[4] = {(bf16_t)xr[i].x, (bf16_t)xr[i].y, (bf16_t)xr[i].z, (bf16_t)xr[i].w};
      *(uint2*)(buf + rw * 128 + (((lane & 15) * 8) ^ ((rw & 7) << 4))) = *(const uint2*)t4;
    }
    asm volatile("s_waitcnt lgkmcnt(0)" ::: "memory");
    __builtin_amdgcn_sched_barrier(0);
  };

  auto computeX = [&](int sub) {
    const char* buf = myx + sub * 2048;
#pragma unroll
    for (int ks = 0; ks < 2; ++ks) {
      bf16x8 af = *(const bf16x8*)(buf + l15 * 128 + ((ks * 64 + g * 16) ^ ((l15 & 7) << 4)));
#pragma unroll
      for (int ct = 0; ct < 4; ++ct)
        acc[ct] = mfma16(af, Wf[ct][sub * 2 + ks], acc[ct]);
    }
  };

  int t0 = blockIdx.x * 3;
  int cur_p = t0 >> 9;
  loadW(cur_p);
  issueX(t0, 0, xA);

#pragma unroll 1
  for (int T = 0; T < 3; ++T) {
    int t = t0 + T;
    int p = t >> 9, lt = t & 511;
    if (p != cur_p) { loadW(p); cur_p = p; }
    issueX(t, 1, xB);
    writeX(xA, 0);
    computeX(0);
    if (T < 2) issueX(t + 1, 0, xA);
    writeX(xB, 1);
    computeX(1);

    // ---- 8-way k-merge + output ----
#pragma unroll
    for (int ct = 0; ct < 4; ++ct)
#pragma unroll
      for (int r = 0; r < 4; ++r)
        Msm[w][g * 4 + r][ct * 16 + l15] = (bf16_t)acc[ct][r];
#pragma unroll
    for (int ct = 0; ct < 4; ++ct) acc[ct] = (f32x4){0.f, 0.f, 0.f, 0.f};
    __syncthreads();

    int row = tid >> 5, c0 = (tid & 31) * 2;
    float s0 = 0.f, s1 = 0.f;
#pragma unroll
    for (int w2 = 0; w2 < 8; ++w2) {
      uint32_t u = *(const uint32_t*)&Msm[w2][row][c0];
      s0 += bf2f((uint16_t)u);
      s1 += bf2f((uint16_t)(u >> 16));
    }

    if (p < 2) {
      bf16_t* Ob = (p == 0) ? Qb : Kb;
      bf16_t o2[2] = {(bf16_t)s0, (bf16_t)s1};
      *(uint32_t*)&Ob[(size_t)(lt * 16 + row) * 64 + c0] = *(const uint32_t*)o2;
      __syncthreads();                       // protect Msm before next tile's writes
    } else {
      __syncthreads();                       // reduce-reads done -> overlay allowed
      bf16_t* Vsm = (bf16_t*)&Msm[0][0][0];  // [16 s][64 d], stride 72
      bf16_t o2[2] = {(bf16_t)s0, (bf16_t)s1};
      *(uint32_t*)&Vsm[row * 72 + c0] = *(const uint32_t*)o2;
      __syncthreads();
      if (tid < 128) {
        int d = tid >> 1, h = tid & 1;
        int b = lt >> 7;
        int s_ = (lt & 127) * 16 + h * 8;
        bf16_t tmp[8];
#pragma unroll
        for (int i = 0; i < 8; ++i) tmp[i] = Vsm[(h * 8 + i) * 72 + d];
        *(uint4*)(Vt + ((size_t)(b * 64 + d)) * 2048 + s_) = *(const uint4*)tmp;
      }
      __syncthreads();
    }
  }
}

// ---------------- kernel 2: causal flash attention, QBLK=32, KV-split 8 waves ------
// grid (64, 4), block 512 (8 waves), ~1 block/CU. Block owns 32 q-rows (2 row-groups
// per wave); wave w handles KV tiles w, w+8, ... with private flash state; merged at
// the end via LDS. K/V frags straight from L2/L3; no barriers in the main loop.
#define NW 8
__global__ __launch_bounds__(512) void attn_kernel(
    const bf16_t* __restrict__ Qb, const bf16_t* __restrict__ Kb,
    const bf16_t* __restrict__ Vt, float* __restrict__ Out) {
  __shared__ alignas(16) char Psm[NW * 4096];   // per-wave 32x64 P tiles (swizzled)
  __shared__ float accL[NW][32][64];            // 64 KB
  __shared__ float mL[NW][32];
  __shared__ float lL[NW][32];

  int b = blockIdx.y;
  int x = blockIdx.x;
  int qt = (b >= 2) ? (63 - x) : x;    // pair heavy+light across CUs
  int q0 = qt * 32;
  int tid = threadIdx.x;
  int w = tid >> 6, lane = tid & 63;
  int l15 = lane & 15, g = lane >> 4;
  char* Pw = Psm + w * 4096;

  bf16x8 qf[2][2];
#pragma unroll
  for (int h = 0; h < 2; ++h) {
    size_t qrow = (size_t)(b * 2048 + q0 + h * 16 + l15) * 64;
    qf[h][0] = *(const bf16x8*)(Qb + qrow + g * 8);
    qf[h][1] = *(const bf16x8*)(Qb + qrow + 32 + g * 8);
  }

  float m_run[2][4], l_run[2][4];
  f32x4 acc_o[2][4] = {};
#pragma unroll
  for (int h = 0; h < 2; ++h)
#pragma unroll
    for (int r = 0; r < 4; ++r) { m_run[h][r] = -1e30f; l_run[h][r] = 0.f; }

  int ntiles = (q0 + 95) >> 6;         // ceil((q0+32)/64)
  const bf16_t* kbase = Kb + (size_t)b * 2048 * 64;
  const bf16_t* vbase = Vt + (size_t)b * 64 * 2048;

  for (int t = w; t < ntiles; t += NW) {
    int kv0 = t * 64;
    // S = Q K^T  (K frags shared across the two row-groups)
    f32x4 s[2][4] = {};
#pragma unroll
    for (int ct = 0; ct < 4; ++ct) {
      const bf16_t* kr = kbase + (size_t)(kv0 + ct * 16 + l15) * 64 + g * 8;
      bf16x8 kf0 = *(const bf16x8*)kr;
      bf16x8 kf1 = *(const bf16x8*)(kr + 32);
#pragma unroll
      for (int h = 0; h < 2; ++h) {
        s[h][ct] = mfma16(qf[h][0], kf0, s[h][ct]);
        s[h][ct] = mfma16(qf[h][1], kf1, s[h][ct]);
      }
    }
    if (t == ntiles - 1) {  // diagonal tile: causal mask
#pragma unroll
      for (int h = 0; h < 2; ++h)
#pragma unroll
        for (int ct = 0; ct < 4; ++ct)
#pragma unroll
          for (int r = 0; r < 4; ++r) {
            int kg_ = kv0 + ct * 16 + l15;
            int qg_ = q0 + h * 16 + g * 4 + r;
            if (kg_ > qg_) s[h][ct][r] = -1e30f;
          }
    }

    // online softmax (row = h*16 + g*4 + r)
#pragma unroll
    for (int h = 0; h < 2; ++h)
#pragma unroll
      for (int r = 0; r < 4; ++r) {
        float mx = fmaxf(fmaxf(s[h][0][r], s[h][1][r]), fmaxf(s[h][2][r], s[h][3][r]));
        mx = fmaxf(mx, __shfl_xor(mx, 1, 64));
        mx = fmaxf(mx, __shfl_xor(mx, 2, 64));
        mx = fmaxf(mx, __shfl_xor(mx, 4, 64));
        mx = fmaxf(mx, __shfl_xor(mx, 8, 64));
        float mnew = fmaxf(m_run[h][r], mx);
        float scale = exp2f((m_run[h][r] - mnew) * L2E);
        m_run[h][r] = mnew;
        float ps = 0.f;
        int qrl = h * 16 + g * 4 + r;
        char* pb = Pw + qrl * 128;
        int swp = (qrl & 7) << 4;
#pragma unroll
        for (int ct = 0; ct < 4; ++ct) {
          float p = exp2f((s[h][ct][r] - mnew) * L2E);
          ps += p;
          *(bf16_t*)(pb + ((ct * 32 + l15 * 2) ^ swp)) = (bf16_t)p;
        }
        ps += __shfl_xor(ps, 1, 64);
        ps += __shfl_xor(ps, 2, 64);
        ps += __shfl_xor(ps, 4, 64);
        ps += __shfl_xor(ps, 8, 64);
        l_run[h][r] = l_run[h][r] * scale + ps;
#pragma unroll
        for (int dt = 0; dt < 4; ++dt) acc_o[h][dt][r] *= scale;
      }

    // O += P V   (V frags shared across the two row-groups)
    int swpr = (l15 & 7) << 4;
#pragma unroll
    for (int ks = 0; ks < 2; ++ks) {
      bf16x8 pf0 = *(const bf16x8*)(Pw + l15 * 128 + ((ks * 64 + g * 16) ^ swpr));
      bf16x8 pf1 = *(const bf16x8*)(Pw + (16 + l15) * 128 + ((ks * 64 + g * 16) ^ swpr));
#pragma unroll
      for (int dt = 0; dt < 4; ++dt) {
        const bf16_t* vr = vbase + (size_t)(dt * 16 + l15) * 2048 + kv0 + ks * 32 + g * 8;
        bf16x8 vf = *(const bf16x8*)vr;
        acc_o[0][dt] = mfma16(pf0, vf, acc_o[0][dt]);
        acc_o[1][dt] = mfma16(pf1, vf, acc_o[1][dt]);
      }
    }
  }

  // publish per-wave partial state
  if (l15 == 0) {
#pragma unroll
    for (int h = 0; h < 2; ++h)
#pragma unroll
      for (int r = 0; r < 4; ++r) {
        mL[w][h * 16 + g * 4 + r] = m_run[h][r];
        lL[w][h * 16 + g * 4 + r] = l_run[h][r];
      }
  }
#pragma unroll
  for (int h = 0; h < 2; ++h)
#pragma unroll
    for (int dt = 0; dt < 4; ++dt)
#pragma unroll
      for (int r = 0; r < 4; ++r)
        accL[w][h * 16 + g * 4 + r][dt * 16 + l15] = acc_o[h][dt][r];
  __syncthreads();

  // merge 8 partials: thread -> (row = tid>>4, 4 d's = (tid&15)*4)
  int row = tid >> 4, c0 = (tid & 15) * 4;
  float M = -1e30f;
#pragma unroll
  for (int w2 = 0; w2 < NW; ++w2) M = fmaxf(M, mL[w2][row]);
  float L = 0.f;
  f32x4 o = {0.f, 0.f, 0.f, 0.f};
#pragma unroll
  for (int w2 = 0; w2 < NW; ++w2) {
    float sc = exp2f((mL[w2][row] - M) * L2E);
    L += lL[w2][row] * sc;
    f32x4 a = *(const f32x4*)&accL[w2][row][c0];
    o[0] += sc * a[0]; o[1] += sc * a[1]; o[2] += sc * a[2]; o[3] += sc * a[3];
  }
  float inv = 1.0f / L;
  float4 o4 = {o[0] * inv, o[1] * inv, o[2] * inv, o[3] * inv};
  *(float4*)&Out[(size_t)(b * 2048 + q0 + row) * 64 + c0] = o4;
}

extern "C" void kernel_launch(void* const* d_in, const int* in_sizes, int n_in,
                              void* d_out, int out_size, void* d_ws, size_t ws_size,
                              hipStream_t stream) {
  const float* Xk = (const float*)d_in[0];
  const float* Xv = (const float*)d_in[1];
  const float* Xq = (const float*)d_in[2];
  const float* Wq = (const float*)d_in[3];
  const float* Wk = (const float*)d_in[4];
  const float* Wv = (const float*)d_in[5];
  float* Out = (float*)d_out;

  bf16_t* ws = (bf16_t*)d_ws;
  bf16_t* Qb = ws;                 // [8192][64]   bf16, pre-scaled by 0.125
  bf16_t* Kb = ws + 524288;        // [8192][64]   bf16
  bf16_t* Vt = ws + 1048576;       // [4][64][2048] bf16 (V transposed)
  bf16_t* Wt = ws + 1572864;       // [3][64][1024] bf16 (weights transposed)

  wt_kernel<<<dim3(768), dim3(256), 0, stream>>>(Wq, Wk, Wv, Wt);
  proj_kernel<<<dim3(512), dim3(512), 0, stream>>>(Xq, Xk, Xv, Wt, Qb, Kb, Vt);
  attn_kernel<<<dim3(64, 4), dim3(512), 0, stream>>>(Qb, Kb, Vt, Out);
}